// Round 4
// baseline (869.336 us; speedup 1.0000x reference)
//
#include <hip/hip_runtime.h>
#include <stdint.h>

#define N_NODES 100000
#define N_EDGES 3200000
#define N_REL   16
// EMB=32, N_CLS=50, BATCH=1024

typedef __attribute__((ext_vector_type(8))) short  short8;
typedef __attribute__((ext_vector_type(4))) float  f32x4;

static __device__ __forceinline__ unsigned short f32_to_bf16(float f) {
    union { float f; unsigned int u; } v; v.f = f;
    unsigned int u = v.u;
    unsigned int r = u + 0x7FFFu + ((u >> 16) & 1u);   // RNE
    return (unsigned short)(r >> 16);
}

// ---------------- histogram: deg[(rel,src)] and cnt[src] ----------------
__global__ void k_hist(const int* __restrict__ src, const int* __restrict__ rel,
                       int* __restrict__ deg, int* __restrict__ cnt) {
    int stride = gridDim.x * blockDim.x;
    for (int e = blockIdx.x * blockDim.x + threadIdx.x; e < N_EDGES; e += stride) {
        int s = src[e], r = rel[e];
        atomicAdd(&deg[r * N_NODES + s], 1);
        atomicAdd(&cnt[s], 1);
    }
}

// ---------------- 3-kernel exclusive scan over cnt[100000] ----------------
__global__ void k_scan1(const int* __restrict__ cnt, int* __restrict__ offs,
                        int* __restrict__ bsum) {
    __shared__ int sd[256];
    int tid = threadIdx.x;
    int idx = blockIdx.x * 256 + tid;
    int v = (idx < N_NODES) ? cnt[idx] : 0;
    sd[tid] = v; __syncthreads();
    int x = v;
    for (int off = 1; off < 256; off <<= 1) {
        int t = (tid >= off) ? sd[tid - off] : 0;
        __syncthreads();
        x += t; sd[tid] = x;
        __syncthreads();
    }
    if (idx < N_NODES) offs[idx] = x - v;
    if (tid == 255) bsum[blockIdx.x] = x;
}

__global__ void k_scan2(int* __restrict__ bsum) {   // NB = 391 blocks
    __shared__ int sd[512];
    int tid = threadIdx.x;
    int v = (tid < 391) ? bsum[tid] : 0;
    sd[tid] = v; __syncthreads();
    int x = v;
    for (int off = 1; off < 512; off <<= 1) {
        int t = (tid >= off) ? sd[tid - off] : 0;
        __syncthreads();
        x += t; sd[tid] = x;
        __syncthreads();
    }
    if (tid < 391) bsum[tid] = x - v;               // exclusive
}

__global__ void k_scan3(int* __restrict__ offs, const int* __restrict__ bsum,
                        int* __restrict__ cursor) {
    int idx = blockIdx.x * 256 + threadIdx.x;
    if (idx >= N_NODES) return;
    int v = offs[idx] + bsum[idx >> 8];
    offs[idx] = v; cursor[idx] = v;
}

// ---------------- inv[(rel,src)] = 1/deg ----------------
__global__ void k_inv(const int* __restrict__ deg, float* __restrict__ inv) {
    int i = blockIdx.x * 256 + threadIdx.x;
    if (i >= N_REL * N_NODES) return;
    int d = deg[i];
    inv[i] = d ? 1.0f / (float)d : 0.f;
}

// ---------------- P[node][r*32+i] = (W1[r] @ emb0[node])_i, bf16 ----------------
// GEMM: A = emb0 (M=node, K=32), B[k][col] = Wcat[col][k], Wcat row (r*32+i) = W1[r][i][:].
__global__ __launch_bounds__(256) void k_pgemm(const float* __restrict__ emb0,
                                               const float* __restrict__ W1,
                                               unsigned short* __restrict__ P,
                                               int nwaves) {
    int tid  = blockIdx.x * 256 + threadIdx.x;
    int w    = tid >> 6;
    int lane = threadIdx.x & 63;
    int col16 = lane & 15, krow = lane >> 4;

    short8 bfr[32];
#pragma unroll
    for (int nt = 0; nt < 32; ++nt) {
        const float* bp = W1 + (nt * 16 + col16) * 32 + krow * 8;
        short8 s;
#pragma unroll
        for (int e = 0; e < 8; ++e) s[e] = (short)f32_to_bf16(bp[e]);
        bfr[nt] = s;
    }
    const int NTILES = N_NODES / 16;   // 6250 exact
    for (int tile = w; tile < NTILES; tile += nwaves) {
        int n0 = tile * 16;
        const float* ap = emb0 + (n0 + col16) * 32 + krow * 8;
        short8 a;
#pragma unroll
        for (int e = 0; e < 8; ++e) a[e] = (short)f32_to_bf16(ap[e]);
#pragma unroll
        for (int nt = 0; nt < 32; ++nt) {
            f32x4 c = {0.f, 0.f, 0.f, 0.f};
            c = __builtin_amdgcn_mfma_f32_16x16x32_bf16(a, bfr[nt], c, 0, 0, 0);
#pragma unroll
            for (int r = 0; r < 4; ++r) {
                int node = n0 + krow * 4 + r;                 // C row
                P[node * 512 + nt * 16 + col16] = f32_to_bf16(c[r]);  // C col
            }
        }
    }
}

// ---------------- counting-sort scatter by src ----------------
__global__ void k_scatter(const int* __restrict__ src, const int* __restrict__ rel,
                          const int* __restrict__ dst, int* __restrict__ cursor,
                          unsigned int* __restrict__ sorted_rd, int* __restrict__ sorted_src) {
    int stride = gridDim.x * blockDim.x;
    for (int e = blockIdx.x * blockDim.x + threadIdx.x; e < N_EDGES; e += stride) {
        int s = src[e];
        int pos = atomicAdd(&cursor[s], 1);
        sorted_rd[pos] = ((unsigned)rel[e] << 17) | (unsigned)dst[e];
        if (s < 1024) sorted_src[pos] = s;   // only layer-2 edges need src back-ref
    }
}

// ---------------- layer-1 aggregate: wave per node, no atomics ----------------
__global__ __launch_bounds__(256) void k_agg1(const unsigned int* __restrict__ sorted_rd,
                                              const int* __restrict__ offs,
                                              const int* __restrict__ cnt,
                                              const float* __restrict__ inv,
                                              const unsigned short* __restrict__ P,
                                              float* __restrict__ h1) {
    int node = blockIdx.x * 4 + (threadIdx.x >> 6);   // grid 25000 x 256 = 100000 waves
    int lane = threadIdx.x & 63;
    int i = lane & 31, h = lane >> 5;
    int start = offs[node], end = start + cnt[node];
    float acc = 0.f;
    for (int t = start + h; t < end; t += 2) {
        unsigned int pk = sorted_rd[t];
        int r = (int)(pk >> 17), d = (int)(pk & 0x1FFFFu);
        float val = inv[r * N_NODES + node];
        unsigned int pu = (unsigned int)P[d * 512 + r * 32 + i];
        union { unsigned int u; float f; } cv; cv.u = pu << 16;
        acc += val * cv.f;
    }
    acc += __shfl_xor(acc, 32, 64);
    if (h == 0) h1[node * 32 + i] = fmaxf(acc, 0.f);   // relu fused
}

// ---------------- layer-2 aggregate: agg2[s][r*32+j] += val * h1relu[d][j] ----------------
// Only edges with src<1024 (sorted[0..E2)). ~1M scattered f32 atomics into 2 MB — cheap.
__global__ void k_agg2(const unsigned int* __restrict__ sorted_rd,
                       const int* __restrict__ sorted_src,
                       const int* __restrict__ offs, const int* __restrict__ cnt,
                       const float* __restrict__ inv, const float* __restrict__ h1,
                       float* __restrict__ agg2) {
    int E2 = offs[1023] + cnt[1023];
    long total = (long)E2 * 32;
    long stride = (long)gridDim.x * blockDim.x;
    for (long t = (long)blockIdx.x * blockDim.x + threadIdx.x; t < total; t += stride) {
        int e = (int)(t >> 5), j = (int)(t & 31);
        unsigned int pk = sorted_rd[e];
        int r = (int)(pk >> 17), d = (int)(pk & 0x1FFFFu);
        int s = sorted_src[e];
        float val = inv[r * N_NODES + s];
        atomicAdd(&agg2[(s << 9) + (r << 5) + j], val * h1[d * 32 + j]);
    }
}

// ---------------- layer-2 transform: h2pre[s][i] = sum_{r,j} W2[r][i][j]*agg2[s][r*32+j] ----
// All f32, 16.8M FMA — trivial. Full overwrite of h2pre (no memset needed).
__global__ void k_h2(const float* __restrict__ agg2, const float* __restrict__ W2,
                     float* __restrict__ h2pre) {
    int t = blockIdx.x * 256 + threadIdx.x;   // 128 blocks x 256 = 1024*32
    int s = t >> 5, i = t & 31;
    const float* arow = agg2 + (s << 9);
    float acc = 0.f;
#pragma unroll 4
    for (int r = 0; r < 16; ++r) {
        const float* wrow = W2 + r * 1024 + i * 32;
        const float* a = arow + r * 32;
#pragma unroll
        for (int j = 0; j < 32; ++j) acc += wrow[j] * a[j];
    }
    h2pre[t] = acc;
}

// ---------------- classifier (relu fused on h2pre) ----------------
__global__ void k_cls(const float* __restrict__ h2pre, const float* __restrict__ cls_w,
                      const float* __restrict__ cls_b, float* __restrict__ out) {
    int t = blockIdx.x * 256 + threadIdx.x;
    int b = t >> 6, c = t & 63;
    if (b >= 1024 || c >= 50) return;
    float acc = cls_b[c];
#pragma unroll
    for (int j = 0; j < 32; ++j)
        acc += fmaxf(h2pre[b * 32 + j], 0.f) * cls_w[c * 32 + j];
    out[b * 50 + c] = acc;
}

extern "C" void kernel_launch(void* const* d_in, const int* in_sizes, int n_in,
                              void* d_out, int out_size, void* d_ws, size_t ws_size,
                              hipStream_t stream) {
    const float* emb0  = (const float*)d_in[0];
    const float* W1    = (const float*)d_in[1];
    const float* W2    = (const float*)d_in[2];
    const float* cls_w = (const float*)d_in[3];
    const float* cls_b = (const float*)d_in[4];
    const int*   src   = (const int*)d_in[5];
    const int*   rel   = (const int*)d_in[6];
    const int*   dst   = (const int*)d_in[7];
    float* out = (float*)d_out;

    char* ws = (char*)d_ws;
    size_t off = 0;
    auto alloc = [&](size_t bytes) -> void* {
        void* p = ws + off;
        off = (off + bytes + 255) & ~((size_t)255);
        return p;
    };
    int*            deg        = (int*)alloc((size_t)N_REL * N_NODES * 4);   // 6.4 MB
    float*          inv        = (float*)alloc((size_t)N_REL * N_NODES * 4); // 6.4 MB
    int*            cnt        = (int*)alloc((size_t)N_NODES * 4);
    int*            offs       = (int*)alloc((size_t)N_NODES * 4);
    int*            cursor     = (int*)alloc((size_t)N_NODES * 4);
    int*            bsum       = (int*)alloc(512 * 4);
    unsigned int*   sorted_rd  = (unsigned int*)alloc((size_t)N_EDGES * 4);  // 12.8 MB
    int*            sorted_src = (int*)alloc((size_t)N_EDGES * 4);           // 12.8 MB
    unsigned short* P          = (unsigned short*)alloc((size_t)N_NODES * 512 * 2); // 102.4 MB
    float*          h1         = (float*)alloc((size_t)N_NODES * 32 * 4);    // 12.8 MB
    float*          agg2       = (float*)alloc((size_t)1024 * 512 * 4);      // 2 MB
    float*          h2pre      = (float*)alloc((size_t)1024 * 32 * 4);

    hipMemsetAsync(deg, 0, (size_t)N_REL * N_NODES * 4, stream);
    hipMemsetAsync(cnt, 0, (size_t)N_NODES * 4, stream);
    hipMemsetAsync(agg2, 0, (size_t)1024 * 512 * 4, stream);

    k_hist   <<<2048, 256, 0, stream>>>(src, rel, deg, cnt);
    k_scan1  <<<391, 256, 0, stream>>>(cnt, offs, bsum);
    k_scan2  <<<1, 512, 0, stream>>>(bsum);
    k_scan3  <<<391, 256, 0, stream>>>(offs, bsum, cursor);
    k_inv    <<<6250, 256, 0, stream>>>(deg, inv);
    k_pgemm  <<<128, 256, 0, stream>>>(emb0, W1, P, 128 * 4);
    k_scatter<<<2048, 256, 0, stream>>>(src, rel, dst, cursor, sorted_rd, sorted_src);
    k_agg1   <<<25000, 256, 0, stream>>>(sorted_rd, offs, cnt, inv, P, h1);
    k_agg2   <<<1024, 256, 0, stream>>>(sorted_rd, sorted_src, offs, cnt, inv, h1, agg2);
    k_h2     <<<128, 256, 0, stream>>>(agg2, W2, h2pre);
    k_cls    <<<256, 256, 0, stream>>>(h2pre, cls_w, cls_b, out);
}

// Round 5
// 751.849 us; speedup vs baseline: 1.1563x; 1.1563x over previous
//
#include <hip/hip_runtime.h>
#include <stdint.h>

#define N_NODES 100000
#define N_EDGES 3200000
#define N_REL   16
#define NBKT    3125        // 100000 / 32 exactly, bucket = src >> 5
// EMB=32, N_CLS=50, BATCH=1024

typedef __attribute__((ext_vector_type(8))) short  short8;
typedef __attribute__((ext_vector_type(4))) float  f32x4;

static __device__ __forceinline__ unsigned short f32_to_bf16(float f) {
    union { float f; unsigned int u; } v; v.f = f;
    unsigned int u = v.u;
    unsigned int r = u + 0x7FFFu + ((u >> 16) & 1u);   // RNE
    return (unsigned short)(r >> 16);
}

// ---------------- cnt[s] histogram (1 atomic/edge, 400 KB target) ----------------
__global__ void k_cnt(const int* __restrict__ src, int* __restrict__ cnt) {
    int stride = gridDim.x * blockDim.x;
    for (int e = blockIdx.x * blockDim.x + threadIdx.x; e < N_EDGES; e += stride)
        atomicAdd(&cnt[src[e]], 1);
}

// ---------------- 3-kernel exclusive scan over cnt[100000] ----------------
__global__ void k_scan1(const int* __restrict__ cnt, int* __restrict__ offs,
                        int* __restrict__ bsum) {
    __shared__ int sd[256];
    int tid = threadIdx.x;
    int idx = blockIdx.x * 256 + tid;
    int v = (idx < N_NODES) ? cnt[idx] : 0;
    sd[tid] = v; __syncthreads();
    int x = v;
    for (int off = 1; off < 256; off <<= 1) {
        int t = (tid >= off) ? sd[tid - off] : 0;
        __syncthreads();
        x += t; sd[tid] = x;
        __syncthreads();
    }
    if (idx < N_NODES) offs[idx] = x - v;
    if (tid == 255) bsum[blockIdx.x] = x;
}

__global__ void k_scan2(int* __restrict__ bsum) {   // 391 block sums
    __shared__ int sd[512];
    int tid = threadIdx.x;
    int v = (tid < 391) ? bsum[tid] : 0;
    sd[tid] = v; __syncthreads();
    int x = v;
    for (int off = 1; off < 512; off <<= 1) {
        int t = (tid >= off) ? sd[tid - off] : 0;
        __syncthreads();
        x += t; sd[tid] = x;
        __syncthreads();
    }
    if (tid < 391) bsum[tid] = x - v;               // exclusive
}

__global__ void k_scan3(int* __restrict__ offs, const int* __restrict__ bsum) {
    int idx = blockIdx.x * 256 + threadIdx.x;
    if (idx >= N_NODES) return;
    offs[idx] = offs[idx] + bsum[idx >> 8];
}

// ---------------- bucket cursors: bcur[b] = offs[b*32] ----------------
__global__ void k_bcur(const int* __restrict__ offs, int* __restrict__ bcur) {
    int b = blockIdx.x * 256 + threadIdx.x;
    if (b < NBKT) bcur[b] = offs[b << 5];
}

// ---------------- pass 1: partition edges into 3125 buckets ----------------
// entry = slow(5) << 21 | rel(4) << 17 | dst(17) — 26 bits, 4 B.
// Writes advance 3125 sequential frontiers -> cache-resident lines, no amplification.
__global__ void k_part(const int* __restrict__ src, const int* __restrict__ rel,
                       const int* __restrict__ dst, int* __restrict__ bcur,
                       unsigned int* __restrict__ part) {
    int stride = gridDim.x * blockDim.x;
    for (int e = blockIdx.x * blockDim.x + threadIdx.x; e < N_EDGES; e += stride) {
        int s = src[e];
        int pos = atomicAdd(&bcur[s >> 5], 1);
        part[pos] = ((unsigned)(s & 31) << 21) | ((unsigned)rel[e] << 17) | (unsigned)dst[e];
    }
}

// ---------------- pass 2: exact placement within bucket + inv2 emission ----------------
// One block per bucket (32 nodes). LDS cursors give exact sorted position (writes land
// in a ~4 KB L2-resident region); LDS (node,rel) histogram replaces the old deg/k_inv.
__global__ __launch_bounds__(256) void k_place(const unsigned int* __restrict__ part,
                                               const int* __restrict__ offs,
                                               unsigned int* __restrict__ sorted_rd,
                                               int* __restrict__ sorted_src,
                                               float* __restrict__ inv2) {
    __shared__ int lcur[32];
    __shared__ int lhist[32 * 16];
    int b = blockIdx.x, tid = threadIdx.x;
    int n0 = b << 5;
    if (tid < 32) lcur[tid] = offs[n0 + tid];        // absolute positions
    if (tid < 256) { lhist[tid] = 0; lhist[tid + 256] = 0; }
    int start = offs[n0];
    int end = (b == NBKT - 1) ? N_EDGES : offs[n0 + 32];
    __syncthreads();
    for (int t = start + tid; t < end; t += 256) {
        unsigned int v = part[t];
        int slow = (int)(v >> 21);
        int p = atomicAdd(&lcur[slow], 1);
        sorted_rd[p] = v & 0x1FFFFFu;                // rel<<17 | dst
        if (b < 32) sorted_src[p] = n0 + slow;       // only nodes < 1024 need src back-ref
        atomicAdd(&lhist[(slow << 4) | ((v >> 17) & 15)], 1);
    }
    __syncthreads();
    for (int t = tid; t < 512; t += 256) {
        int c = lhist[t];
        inv2[((size_t)n0 << 4) + t] = c ? 1.0f / (float)c : 0.f;   // inv2[(n0+j)*16 + r]
    }
}

// ---------------- P[node][r*32+i] = (W1[r] @ emb0[node])_i, bf16 ----------------
__global__ __launch_bounds__(256) void k_pgemm(const float* __restrict__ emb0,
                                               const float* __restrict__ W1,
                                               unsigned short* __restrict__ P,
                                               int nwaves) {
    int tid  = blockIdx.x * 256 + threadIdx.x;
    int w    = tid >> 6;
    int lane = threadIdx.x & 63;
    int col16 = lane & 15, krow = lane >> 4;

    short8 bfr[32];
#pragma unroll
    for (int nt = 0; nt < 32; ++nt) {
        const float* bp = W1 + (nt * 16 + col16) * 32 + krow * 8;
        short8 s;
#pragma unroll
        for (int e = 0; e < 8; ++e) s[e] = (short)f32_to_bf16(bp[e]);
        bfr[nt] = s;
    }
    const int NTILES = N_NODES / 16;   // 6250 exact
    for (int tile = w; tile < NTILES; tile += nwaves) {
        int n0 = tile * 16;
        const float* ap = emb0 + (n0 + col16) * 32 + krow * 8;
        short8 a;
#pragma unroll
        for (int e = 0; e < 8; ++e) a[e] = (short)f32_to_bf16(ap[e]);
#pragma unroll
        for (int nt = 0; nt < 32; ++nt) {
            f32x4 c = {0.f, 0.f, 0.f, 0.f};
            c = __builtin_amdgcn_mfma_f32_16x16x32_bf16(a, bfr[nt], c, 0, 0, 0);
#pragma unroll
            for (int r = 0; r < 4; ++r) {
                int node = n0 + krow * 4 + r;                 // C row
                P[node * 512 + nt * 16 + col16] = f32_to_bf16(c[r]);  // C col
            }
        }
    }
}

// ---------------- layer-1 aggregate: wave per node, no atomics ----------------
__global__ __launch_bounds__(256) void k_agg1(const unsigned int* __restrict__ sorted_rd,
                                              const int* __restrict__ offs,
                                              const int* __restrict__ cnt,
                                              const float* __restrict__ inv2,
                                              const unsigned short* __restrict__ P,
                                              float* __restrict__ h1) {
    int node = blockIdx.x * 4 + (threadIdx.x >> 6);   // 25000 x 256 = 100000 waves
    int lane = threadIdx.x & 63;
    int i = lane & 31, h = lane >> 5;
    int start = offs[node], end = start + cnt[node];
    const float* ivn = inv2 + ((size_t)node << 4);    // 16 floats, one hot line
    float acc = 0.f;
    for (int t = start + h; t < end; t += 2) {
        unsigned int pk = sorted_rd[t];
        int r = (int)(pk >> 17), d = (int)(pk & 0x1FFFFu);
        float val = ivn[r];
        unsigned int pu = (unsigned int)P[d * 512 + r * 32 + i];
        union { unsigned int u; float f; } cv; cv.u = pu << 16;
        acc += val * cv.f;
    }
    acc += __shfl_xor(acc, 32, 64);
    if (h == 0) h1[node * 32 + i] = fmaxf(acc, 0.f);   // relu fused
}

// ---------------- layer-2 aggregate: agg2[s][r*32+j] += val * h1relu[d][j] ----------------
__global__ void k_agg2(const unsigned int* __restrict__ sorted_rd,
                       const int* __restrict__ sorted_src,
                       const int* __restrict__ offs, const int* __restrict__ cnt,
                       const float* __restrict__ inv2, const float* __restrict__ h1,
                       float* __restrict__ agg2) {
    int E2 = offs[1023] + cnt[1023];
    long total = (long)E2 * 32;
    long stride = (long)gridDim.x * blockDim.x;
    for (long t = (long)blockIdx.x * blockDim.x + threadIdx.x; t < total; t += stride) {
        int e = (int)(t >> 5), j = (int)(t & 31);
        unsigned int pk = sorted_rd[e];
        int r = (int)(pk >> 17), d = (int)(pk & 0x1FFFFu);
        int s = sorted_src[e];
        float val = inv2[((size_t)s << 4) + r];
        atomicAdd(&agg2[(s << 9) + (r << 5) + j], val * h1[d * 32 + j]);
    }
}

// ---------------- layer-2 transform: h2pre[s][i] = sum_{r,j} W2[r][i][j]*agg2[s][r*32+j] ----
__global__ void k_h2(const float* __restrict__ agg2, const float* __restrict__ W2,
                     float* __restrict__ h2pre) {
    int t = blockIdx.x * 256 + threadIdx.x;   // 128 x 256 = 1024*32
    int s = t >> 5, i = t & 31;
    const float* arow = agg2 + (s << 9);
    float acc = 0.f;
#pragma unroll 4
    for (int r = 0; r < 16; ++r) {
        const float* wrow = W2 + r * 1024 + i * 32;
        const float* a = arow + r * 32;
#pragma unroll
        for (int j = 0; j < 32; ++j) acc += wrow[j] * a[j];
    }
    h2pre[t] = acc;
}

// ---------------- classifier (relu fused on h2pre) ----------------
__global__ void k_cls(const float* __restrict__ h2pre, const float* __restrict__ cls_w,
                      const float* __restrict__ cls_b, float* __restrict__ out) {
    int t = blockIdx.x * 256 + threadIdx.x;
    int b = t >> 6, c = t & 63;
    if (b >= 1024 || c >= 50) return;
    float acc = cls_b[c];
#pragma unroll
    for (int j = 0; j < 32; ++j)
        acc += fmaxf(h2pre[b * 32 + j], 0.f) * cls_w[c * 32 + j];
    out[b * 50 + c] = acc;
}

extern "C" void kernel_launch(void* const* d_in, const int* in_sizes, int n_in,
                              void* d_out, int out_size, void* d_ws, size_t ws_size,
                              hipStream_t stream) {
    const float* emb0  = (const float*)d_in[0];
    const float* W1    = (const float*)d_in[1];
    const float* W2    = (const float*)d_in[2];
    const float* cls_w = (const float*)d_in[3];
    const float* cls_b = (const float*)d_in[4];
    const int*   src   = (const int*)d_in[5];
    const int*   rel   = (const int*)d_in[6];
    const int*   dst   = (const int*)d_in[7];
    float* out = (float*)d_out;

    char* ws = (char*)d_ws;
    size_t off = 0;
    auto alloc = [&](size_t bytes) -> void* {
        void* p = ws + off;
        off = (off + bytes + 255) & ~((size_t)255);
        return p;
    };
    float*          inv2       = (float*)alloc((size_t)N_NODES * 16 * 4);    // 6.4 MB
    int*            cnt        = (int*)alloc((size_t)N_NODES * 4);
    int*            offs       = (int*)alloc((size_t)N_NODES * 4);
    int*            bsum       = (int*)alloc(512 * 4);
    int*            bcur       = (int*)alloc((size_t)NBKT * 4);
    unsigned int*   sorted_rd  = (unsigned int*)alloc((size_t)N_EDGES * 4);  // 12.8 MB
    int*            sorted_src = (int*)alloc((size_t)N_EDGES * 4);           // 12.8 MB
    unsigned short* P          = (unsigned short*)alloc((size_t)N_NODES * 512 * 2); // 102.4 MB
    float*          h1         = (float*)alloc((size_t)N_NODES * 32 * 4);    // 12.8 MB
    float*          agg2       = (float*)alloc((size_t)1024 * 512 * 4);      // 2 MB
    float*          h2pre      = (float*)alloc((size_t)1024 * 32 * 4);
    // part aliases P: dead before k_pgemm writes P (stream-ordered)
    unsigned int*   part       = (unsigned int*)P;

    hipMemsetAsync(cnt, 0, (size_t)N_NODES * 4, stream);
    hipMemsetAsync(agg2, 0, (size_t)1024 * 512 * 4, stream);

    k_cnt   <<<2048, 256, 0, stream>>>(src, cnt);
    k_scan1 <<<391, 256, 0, stream>>>(cnt, offs, bsum);
    k_scan2 <<<1, 512, 0, stream>>>(bsum);
    k_scan3 <<<391, 256, 0, stream>>>(offs, bsum);
    k_bcur  <<<13, 256, 0, stream>>>(offs, bcur);
    k_part  <<<2048, 256, 0, stream>>>(src, rel, dst, bcur, part);
    k_place <<<NBKT, 256, 0, stream>>>(part, offs, sorted_rd, sorted_src, inv2);
    k_pgemm <<<128, 256, 0, stream>>>(emb0, W1, P, 128 * 4);
    k_agg1  <<<25000, 256, 0, stream>>>(sorted_rd, offs, cnt, inv2, P, h1);
    k_agg2  <<<1024, 256, 0, stream>>>(sorted_rd, sorted_src, offs, cnt, inv2, h1, agg2);
    k_h2    <<<128, 256, 0, stream>>>(agg2, W2, h2pre);
    k_cls   <<<256, 256, 0, stream>>>(h2pre, cls_w, cls_b, out);
}

// Round 6
// 513.583 us; speedup vs baseline: 1.6927x; 1.4639x over previous
//
#include <hip/hip_runtime.h>
#include <stdint.h>

#define N_NODES 100000
#define N_EDGES 3200000
#define N_REL   16
#define NBKT    391         // ceil(100000/256) buckets of 256 nodes (bucket = src >> 8)
#define NBLK    128         // partition blocks; 3.2M/128 = 25000 edges each
#define EPB     25000
// EMB=32, N_CLS=50, BATCH=1024

typedef __attribute__((ext_vector_type(8))) short  short8;
typedef __attribute__((ext_vector_type(4))) float  f32x4;

static __device__ __forceinline__ unsigned short f32_to_bf16(float f) {
    union { float f; unsigned int u; } v; v.f = f;
    unsigned int u = v.u;
    unsigned int r = u + 0x7FFFu + ((u >> 16) & 1u);   // RNE
    return (unsigned short)(r >> 16);
}

// ---------------- phase A: per-block bucket histogram (LDS atomics only) ----------------
__global__ __launch_bounds__(256) void k_histA(const int* __restrict__ src,
                                               int* __restrict__ table) {
    __shared__ int lh[NBKT];
    int tid = threadIdx.x, bid = blockIdx.x;
    for (int t = tid; t < NBKT; t += 256) lh[t] = 0;
    __syncthreads();
    int e0 = bid * EPB;
    for (int e = e0 + tid; e < e0 + EPB; e += 256)
        atomicAdd(&lh[src[e] >> 8], 1);
    __syncthreads();
    for (int t = tid; t < NBKT; t += 256) table[bid * NBKT + t] = lh[t];
}

// ---------------- bucket totals ----------------
__global__ void k_btot(const int* __restrict__ table, int* __restrict__ btot) {
    int b = blockIdx.x * 256 + threadIdx.x;
    if (b >= NBKT) return;
    int s = 0;
    for (int k = 0; k < NBLK; ++k) s += table[k * NBKT + b];
    btot[b] = s;
}

// ---------------- bucket bases: exclusive scan of btot[391] ----------------
__global__ void k_bbase(const int* __restrict__ btot, int* __restrict__ bktbase) {
    __shared__ int sd[512];
    int tid = threadIdx.x;
    int v = (tid < NBKT) ? btot[tid] : 0;
    sd[tid] = v; __syncthreads();
    int x = v;
    for (int off = 1; off < 512; off <<= 1) {
        int t = (tid >= off) ? sd[tid - off] : 0;
        __syncthreads();
        x += t; sd[tid] = x;
        __syncthreads();
    }
    if (tid < NBKT) bktbase[tid] = x - v;
    if (tid == 0) bktbase[NBKT] = N_EDGES;
}

// ---------------- per-(bucket,block) offsets: goff[block][bkt] ----------------
__global__ void k_goff(const int* __restrict__ table, const int* __restrict__ bktbase,
                       int* __restrict__ goff) {
    __shared__ int sd[NBLK];
    int b = blockIdx.x;           // bucket
    int tid = threadIdx.x;        // block index (128 threads)
    int v = table[tid * NBKT + b];
    sd[tid] = v; __syncthreads();
    int x = v;
    for (int off = 1; off < NBLK; off <<= 1) {
        int t = (tid >= off) ? sd[tid - off] : 0;
        __syncthreads();
        x += t; sd[tid] = x;
        __syncthreads();
    }
    goff[tid * NBKT + b] = bktbase[b] + (x - v);
}

// ---------------- phase C: partition into buckets, single-owner write streams ----------
// entry = slow(8) << 21 | rel(4) << 17 | dst(17)
__global__ __launch_bounds__(256) void k_partB(const int* __restrict__ src,
                                               const int* __restrict__ rel,
                                               const int* __restrict__ dst,
                                               const int* __restrict__ goff,
                                               unsigned int* __restrict__ part) {
    __shared__ int lcur[NBKT];
    int tid = threadIdx.x, bid = blockIdx.x;
    for (int t = tid; t < NBKT; t += 256) lcur[t] = goff[bid * NBKT + t];
    __syncthreads();
    int e0 = bid * EPB;
    for (int e = e0 + tid; e < e0 + EPB; e += 256) {
        int s = src[e];
        int pos = atomicAdd(&lcur[s >> 8], 1);
        part[pos] = ((unsigned)(s & 255) << 21) | ((unsigned)rel[e] << 17) | (unsigned)dst[e];
    }
}

// ---------------- k_place: node-exact placement + offs/cnt/inv2 (replaces scans) -------
__global__ __launch_bounds__(256) void k_place(const unsigned int* __restrict__ part,
                                               const int* __restrict__ bktbase,
                                               unsigned int* __restrict__ sorted_rd,
                                               int* __restrict__ sorted_src,
                                               int* __restrict__ offs,
                                               int* __restrict__ cnt,
                                               float* __restrict__ inv2) {
    __shared__ int lhist[256 * 16];    // (node-in-bucket, rel) counts
    __shared__ int sd[256];            // scan temp
    __shared__ int lcur[256];          // node cursors
    int b = blockIdx.x, tid = threadIdx.x;
    int n0 = b << 8;
    int base = bktbase[b], end = bktbase[b + 1];
#pragma unroll
    for (int k = 0; k < 16; ++k) lhist[tid + k * 256] = 0;
    __syncthreads();
    // pass 1: (node,rel) histogram
    for (int t = base + tid; t < end; t += 256)
        atomicAdd(&lhist[part[t] >> 17], 1);   // (slow<<4)|rel, < 4096
    __syncthreads();
    // node counts + exclusive scan over 256 nodes
    int ncnt = 0;
#pragma unroll
    for (int r = 0; r < 16; ++r) ncnt += lhist[(tid << 4) | r];
    sd[tid] = ncnt; __syncthreads();
    int x = ncnt;
    for (int off = 1; off < 256; off <<= 1) {
        int t = (tid >= off) ? sd[tid - off] : 0;
        __syncthreads();
        x += t; sd[tid] = x;
        __syncthreads();
    }
    int nodeoff = base + (x - ncnt);
    lcur[tid] = nodeoff;
    int node = n0 + tid;
    if (node < N_NODES) { offs[node] = nodeoff; cnt[node] = ncnt; }
    // inv2 emission
    for (int t = tid; t < 4096; t += 256) {
        int nd = n0 + (t >> 4);
        if (nd < N_NODES) {
            int c = lhist[t];
            inv2[((size_t)nd << 4) + (t & 15)] = c ? 1.0f / (float)c : 0.f;
        }
    }
    __syncthreads();
    // pass 2: exact placement
    for (int t = base + tid; t < end; t += 256) {
        unsigned int v = part[t];
        int j = (int)(v >> 21);
        int p = atomicAdd(&lcur[j], 1);
        sorted_rd[p] = v & 0x1FFFFFu;
        if (b < 4) sorted_src[p] = n0 + j;    // buckets 0..3 = nodes 0..1023
    }
}

// ---------------- P[node][r*32+i] = (W1[r] @ emb0[node])_i, bf16 ----------------
__global__ __launch_bounds__(256) void k_pgemm(const float* __restrict__ emb0,
                                               const float* __restrict__ W1,
                                               unsigned short* __restrict__ P,
                                               int nwaves) {
    int tid  = blockIdx.x * 256 + threadIdx.x;
    int w    = tid >> 6;
    int lane = threadIdx.x & 63;
    int col16 = lane & 15, krow = lane >> 4;

    short8 bfr[32];
#pragma unroll
    for (int nt = 0; nt < 32; ++nt) {
        const float* bp = W1 + (nt * 16 + col16) * 32 + krow * 8;
        short8 s;
#pragma unroll
        for (int e = 0; e < 8; ++e) s[e] = (short)f32_to_bf16(bp[e]);
        bfr[nt] = s;
    }
    const int NTILES = N_NODES / 16;   // 6250 exact
    for (int tile = w; tile < NTILES; tile += nwaves) {
        int n0 = tile * 16;
        const float* ap = emb0 + (n0 + col16) * 32 + krow * 8;
        short8 a;
#pragma unroll
        for (int e = 0; e < 8; ++e) a[e] = (short)f32_to_bf16(ap[e]);
#pragma unroll
        for (int nt = 0; nt < 32; ++nt) {
            f32x4 c = {0.f, 0.f, 0.f, 0.f};
            c = __builtin_amdgcn_mfma_f32_16x16x32_bf16(a, bfr[nt], c, 0, 0, 0);
#pragma unroll
            for (int r = 0; r < 4; ++r) {
                int node = n0 + krow * 4 + r;                 // C row
                P[node * 512 + nt * 16 + col16] = f32_to_bf16(c[r]);  // C col
            }
        }
    }
}

// ---------------- layer-1 aggregate: wave per node, no atomics ----------------
__global__ __launch_bounds__(256) void k_agg1(const unsigned int* __restrict__ sorted_rd,
                                              const int* __restrict__ offs,
                                              const int* __restrict__ cnt,
                                              const float* __restrict__ inv2,
                                              const unsigned short* __restrict__ P,
                                              float* __restrict__ h1) {
    int node = blockIdx.x * 4 + (threadIdx.x >> 6);   // 25000 x 256 = 100000 waves
    int lane = threadIdx.x & 63;
    int i = lane & 31, h = lane >> 5;
    int start = offs[node], end = start + cnt[node];
    const float* ivn = inv2 + ((size_t)node << 4);    // 16 floats, one hot line
    float acc = 0.f;
    for (int t = start + h; t < end; t += 2) {
        unsigned int pk = sorted_rd[t];
        int r = (int)(pk >> 17), d = (int)(pk & 0x1FFFFu);
        float val = ivn[r];
        unsigned int pu = (unsigned int)P[d * 512 + r * 32 + i];
        union { unsigned int u; float f; } cv; cv.u = pu << 16;
        acc += val * cv.f;
    }
    acc += __shfl_xor(acc, 32, 64);
    if (h == 0) h1[node * 32 + i] = fmaxf(acc, 0.f);   // relu fused
}

// ---------------- layer-2 aggregate: agg2[s][r*32+j] += val * h1relu[d][j] ----------------
__global__ void k_agg2(const unsigned int* __restrict__ sorted_rd,
                       const int* __restrict__ sorted_src,
                       const int* __restrict__ offs, const int* __restrict__ cnt,
                       const float* __restrict__ inv2, const float* __restrict__ h1,
                       float* __restrict__ agg2) {
    int E2 = offs[1023] + cnt[1023];
    long total = (long)E2 * 32;
    long stride = (long)gridDim.x * blockDim.x;
    for (long t = (long)blockIdx.x * blockDim.x + threadIdx.x; t < total; t += stride) {
        int e = (int)(t >> 5), j = (int)(t & 31);
        unsigned int pk = sorted_rd[e];
        int r = (int)(pk >> 17), d = (int)(pk & 0x1FFFFu);
        int s = sorted_src[e];
        float val = inv2[((size_t)s << 4) + r];
        atomicAdd(&agg2[(s << 9) + (r << 5) + j], val * h1[d * 32 + j]);
    }
}

// ---------------- layer-2 transform ----------------
__global__ void k_h2(const float* __restrict__ agg2, const float* __restrict__ W2,
                     float* __restrict__ h2pre) {
    int t = blockIdx.x * 256 + threadIdx.x;   // 128 x 256 = 1024*32
    int s = t >> 5, i = t & 31;
    const float* arow = agg2 + (s << 9);
    float acc = 0.f;
#pragma unroll 4
    for (int r = 0; r < 16; ++r) {
        const float* wrow = W2 + r * 1024 + i * 32;
        const float* a = arow + r * 32;
#pragma unroll
        for (int j = 0; j < 32; ++j) acc += wrow[j] * a[j];
    }
    h2pre[t] = acc;
}

// ---------------- classifier ----------------
__global__ void k_cls(const float* __restrict__ h2pre, const float* __restrict__ cls_w,
                      const float* __restrict__ cls_b, float* __restrict__ out) {
    int t = blockIdx.x * 256 + threadIdx.x;
    int b = t >> 6, c = t & 63;
    if (b >= 1024 || c >= 50) return;
    float acc = cls_b[c];
#pragma unroll
    for (int j = 0; j < 32; ++j)
        acc += fmaxf(h2pre[b * 32 + j], 0.f) * cls_w[c * 32 + j];
    out[b * 50 + c] = acc;
}

extern "C" void kernel_launch(void* const* d_in, const int* in_sizes, int n_in,
                              void* d_out, int out_size, void* d_ws, size_t ws_size,
                              hipStream_t stream) {
    const float* emb0  = (const float*)d_in[0];
    const float* W1    = (const float*)d_in[1];
    const float* W2    = (const float*)d_in[2];
    const float* cls_w = (const float*)d_in[3];
    const float* cls_b = (const float*)d_in[4];
    const int*   src   = (const int*)d_in[5];
    const int*   rel   = (const int*)d_in[6];
    const int*   dst   = (const int*)d_in[7];
    float* out = (float*)d_out;

    char* ws = (char*)d_ws;
    size_t off = 0;
    auto alloc = [&](size_t bytes) -> void* {
        void* p = ws + off;
        off = (off + bytes + 255) & ~((size_t)255);
        return p;
    };
    float*          inv2       = (float*)alloc((size_t)N_NODES * 16 * 4);    // 6.4 MB
    int*            offs       = (int*)alloc((size_t)N_NODES * 4);
    int*            cnt        = (int*)alloc((size_t)N_NODES * 4);
    int*            table      = (int*)alloc((size_t)NBLK * NBKT * 4);       // 200 KB
    int*            btot       = (int*)alloc((size_t)NBKT * 4);
    int*            bktbase    = (int*)alloc((size_t)(NBKT + 1) * 4);
    int*            goff       = (int*)alloc((size_t)NBLK * NBKT * 4);       // 200 KB
    unsigned int*   sorted_rd  = (unsigned int*)alloc((size_t)N_EDGES * 4);  // 12.8 MB
    int*            sorted_src = (int*)alloc((size_t)N_EDGES * 4);           // 12.8 MB
    unsigned short* P          = (unsigned short*)alloc((size_t)N_NODES * 512 * 2); // 102.4 MB
    float*          h1         = (float*)alloc((size_t)N_NODES * 32 * 4);    // 12.8 MB
    float*          agg2       = (float*)alloc((size_t)1024 * 512 * 4);      // 2 MB
    float*          h2pre      = (float*)alloc((size_t)1024 * 32 * 4);
    // part aliases P: dead before k_pgemm writes P (stream-ordered)
    unsigned int*   part       = (unsigned int*)P;

    hipMemsetAsync(agg2, 0, (size_t)1024 * 512 * 4, stream);

    k_histA <<<NBLK, 256, 0, stream>>>(src, table);
    k_btot  <<<2, 256, 0, stream>>>(table, btot);
    k_bbase <<<1, 512, 0, stream>>>(btot, bktbase);
    k_goff  <<<NBKT, NBLK, 0, stream>>>(table, bktbase, goff);
    k_partB <<<NBLK, 256, 0, stream>>>(src, rel, dst, goff, part);
    k_place <<<NBKT, 256, 0, stream>>>(part, bktbase, sorted_rd, sorted_src, offs, cnt, inv2);
    k_pgemm <<<128, 256, 0, stream>>>(emb0, W1, P, 128 * 4);
    k_agg1  <<<25000, 256, 0, stream>>>(sorted_rd, offs, cnt, inv2, P, h1);
    k_agg2  <<<1024, 256, 0, stream>>>(sorted_rd, sorted_src, offs, cnt, inv2, h1, agg2);
    k_h2    <<<128, 256, 0, stream>>>(agg2, W2, h2pre);
    k_cls   <<<256, 256, 0, stream>>>(h2pre, cls_w, cls_b, out);
}